// Round 6
// baseline (235.042 us; speedup 1.0000x reference)
//
#include <hip/hip_runtime.h>
#include <hip/hip_bf16.h>

#define N_TOK 32768
#define DIM   192
#define HID   384
#define NEXP  8

#define KT1 6     // DIM/32
#define JT1 24    // HID/16
#define KT2 12    // HID/32
#define JT2 12    // DIM/16
#define EPSV 2.220446049250313e-16f

typedef __attribute__((ext_vector_type(8))) short short8;
typedef __attribute__((ext_vector_type(4))) float f32x4;

static __device__ __forceinline__ short f2bf(float f) {
    union { __hip_bfloat16 h; short s; } u;
    u.h = __float2bfloat16(f);
    return u.s;
}

// ---------------------------------------------------------------------------
// Gating, 4 lanes per token: logits = [x,emb] @ w_gate ; top-2 ; softmax ;
// scatter to expert lists; lanes q=0,1 also emit bf16 x rows.
// ---------------------------------------------------------------------------
template<bool WXB>
__global__ __launch_bounds__(256) void gate_kernel(
    const float* __restrict__ x, const float* __restrict__ emb,
    const float* __restrict__ wg,
    int* __restrict__ counts, int* __restrict__ toks, float* __restrict__ gates,
    short* __restrict__ xb)
{
    __shared__ float wgs[2 * DIM * NEXP];   // 12 KB
    __shared__ int cnt[NEXP];
    __shared__ int base[NEXP];
    int tid = threadIdx.x;
    for (int i = tid; i < 2 * DIM * NEXP; i += 256) wgs[i] = wg[i];
    if (tid < NEXP) cnt[tid] = 0;
    __syncthreads();

    int t = blockIdx.x * 64 + (tid >> 2);
    int q = tid & 3;
    const float* src = ((q < 2) ? x : emb) + (size_t)t * DIM + (q & 1) * 96;
    short* xrow = (WXB && q < 2) ? (xb + (size_t)t * DIM + q * 96) : nullptr;

    float acc[NEXP];
#pragma unroll
    for (int e = 0; e < NEXP; ++e) acc[e] = 0.f;

#pragma unroll 3
    for (int i = 0; i < 12; ++i) {           // 8 concat-dims per iter
        float4 v0 = reinterpret_cast<const float4*>(src)[2 * i];
        float4 v1 = reinterpret_cast<const float4*>(src)[2 * i + 1];
        if (WXB && q < 2) {
            short8 s;
            s[0] = f2bf(v0.x); s[1] = f2bf(v0.y); s[2] = f2bf(v0.z); s[3] = f2bf(v0.w);
            s[4] = f2bf(v1.x); s[5] = f2bf(v1.y); s[6] = f2bf(v1.z); s[7] = f2bf(v1.w);
            *reinterpret_cast<short8*>(xrow + i * 8) = s;
        }
        const float* wr = &wgs[(q * 96 + i * 8) * NEXP];
        float vs[8] = {v0.x, v0.y, v0.z, v0.w, v1.x, v1.y, v1.z, v1.w};
#pragma unroll
        for (int u = 0; u < 8; ++u)
#pragma unroll
            for (int e = 0; e < NEXP; ++e)
                acc[e] += vs[u] * wr[u * NEXP + e];
    }

    // reduce across the 4 lanes of this token
#pragma unroll
    for (int e = 0; e < NEXP; ++e) {
        acc[e] += __shfl_xor(acc[e], 1);
        acc[e] += __shfl_xor(acc[e], 2);
    }

    int i1 = 0, i2 = -1, p1 = 0, p2 = 0;
    float g1 = 0.f, g2 = 0.f;
    if (q == 0) {
        float l1 = acc[0];
#pragma unroll
        for (int e = 1; e < NEXP; ++e) { if (acc[e] > l1) { l1 = acc[e]; i1 = e; } }
        float l2 = -1e30f;
#pragma unroll
        for (int e = 0; e < NEXP; ++e) { if (e != i1 && acc[e] > l2) { l2 = acc[e]; i2 = e; } }
        g1 = 1.f / (1.f + expf(l2 - l1));
        g2 = 1.f - g1;
        p1 = atomicAdd(&cnt[i1], 1);
        p2 = atomicAdd(&cnt[i2], 1);
    }
    __syncthreads();
    if (tid < NEXP) base[tid] = atomicAdd(&counts[tid], cnt[tid]);
    __syncthreads();
    if (q == 0) {
        int o1 = base[i1] + p1;
        int o2 = base[i2] + p2;
        toks[i1 * N_TOK + o1]  = (t << 1);
        gates[i1 * N_TOK + o1] = g1;
        toks[i2 * N_TOK + o2]  = (t << 1) | 1;
        gates[i2 * N_TOK + o2] = g2;
    }
}

// ---------------------------------------------------------------------------
// Pack w1/w2 -> bf16 MFMA B-fragment order: [e][kt][jt][lane][8]
// Coalesced float4 source reads; scattered 2B writes.
// frag elem (k,j): kt=k>>5, jt=j>>4, lane=(j&15)|(((k>>3)&3)<<4), t=k&7
// ---------------------------------------------------------------------------
__global__ __launch_bounds__(256) void pack_kernel(
    const float* __restrict__ w1, const float* __restrict__ w2,
    short* __restrict__ pb1, short* __restrict__ pb2)
{
    const int Q = NEXP * DIM * HID / 4;   // 147456 threads per tensor
    int i = blockIdx.x * 256 + threadIdx.x;
    if (i < Q) {
        int idx = i * 4;
        int e = idx / (DIM * HID);
        int r = idx - e * (DIM * HID);
        int k = r / HID, j0 = r - k * HID;
        float4 v = *reinterpret_cast<const float4*>(w1 + idx);
        const float* vp = reinterpret_cast<const float*>(&v);
        int lg = (k >> 3) & 3, tt = k & 7;
        short* base = pb1 + ((size_t)(e * KT1 + (k >> 5)) * JT1) * 512;
#pragma unroll
        for (int d = 0; d < 4; ++d) {
            int j = j0 + d;
            base[(j >> 4) * 512 + (((j & 15) | (lg << 4)) << 3) + tt] = f2bf(vp[d]);
        }
    } else if (i < 2 * Q) {
        int idx = (i - Q) * 4;
        int e = idx / (HID * DIM);
        int r = idx - e * (HID * DIM);
        int k = r / DIM, j0 = r - k * DIM;
        float4 v = *reinterpret_cast<const float4*>(w2 + idx);
        const float* vp = reinterpret_cast<const float*>(&v);
        int lg = (k >> 3) & 3, tt = k & 7;
        short* base = pb2 + ((size_t)(e * KT2 + (k >> 5)) * JT2) * 512;
#pragma unroll
        for (int d = 0; d < 4; ++d) {
            int j = j0 + d;
            base[(j >> 4) * 512 + (((j & 15) | (lg << 4)) << 3) + tt] = f2bf(vp[d]);
        }
    }
}

// ---------------------------------------------------------------------------
// Fused expert MLP: per 64-row tile of one expert, per wave (16 rows):
//   Phase A: H = gelu(X @ w1 + b1) -> private LDS (XOR-swizzled)
//   Phase B: slot[tk] = gate * exp(H @ w2 + b2)
// B-operands streamed from L2/L3-hot packed weights. No main-loop barriers.
// ---------------------------------------------------------------------------
template<bool USE_XB>
__global__ __launch_bounds__(256, 2) void fused_kernel(
    const float* __restrict__ x, const short* __restrict__ xb,
    const short* __restrict__ pb1, const short* __restrict__ pb2,
    const float* __restrict__ b1, const float* __restrict__ b2,
    const int* __restrict__ counts, const int* __restrict__ toks,
    const float* __restrict__ gates, float* __restrict__ slot)
{
    int e  = blockIdx.x >> 9;
    int m0 = (blockIdx.x & 511) * 64;
    int cnt = counts[e];
    if (m0 >= cnt) return;

    __shared__ __align__(16) char hl[4][12288];   // 12KB H tile per wave
    __shared__ int ts[64];
    __shared__ float gs[64];

    int tid = threadIdx.x, wave = tid >> 6, lane = tid & 63;
    if (tid < 64) {
        int idx = m0 + tid;
        bool v = idx < cnt;
        ts[tid] = toks[e * N_TOK + (v ? idx : cnt - 1)];
        gs[tid] = v ? gates[e * N_TOK + idx] : 0.f;
    }
    __syncthreads();

    int lrow = lane & 15, lgrp = lane >> 4;
    int tok = ts[wave * 16 + lrow] >> 1;

    // ---- A1 fragments (this lane's row of X, bf16) ----
    short8 a1[KT1];
    if (USE_XB) {
        const char* xr = (const char*)xb + (size_t)tok * 384 + lgrp * 16;
#pragma unroll
        for (int kt = 0; kt < KT1; ++kt) a1[kt] = *(const short8*)(xr + kt * 64);
    } else {
        const char* xr = (const char*)x + (size_t)tok * 768 + lgrp * 32;
#pragma unroll
        for (int kt = 0; kt < KT1; ++kt) {
            float4 v0 = *(const float4*)(xr + kt * 128);
            float4 v1 = *(const float4*)(xr + kt * 128 + 16);
            short8 s;
            s[0] = f2bf(v0.x); s[1] = f2bf(v0.y); s[2] = f2bf(v0.z); s[3] = f2bf(v0.w);
            s[4] = f2bf(v1.x); s[5] = f2bf(v1.y); s[6] = f2bf(v1.z); s[7] = f2bf(v1.w);
            a1[kt] = s;
        }
    }

    // ---- Phase A: H = X @ w1 (stream B from global) ----
    f32x4 acc1[JT1];
#pragma unroll
    for (int j = 0; j < JT1; ++j) acc1[j] = (f32x4){0.f, 0.f, 0.f, 0.f};
    const short8* p1 = reinterpret_cast<const short8*>(pb1) + (size_t)e * (KT1 * JT1 * 64) + lane;
#pragma unroll
    for (int kt = 0; kt < KT1; ++kt)
#pragma unroll
        for (int jt = 0; jt < JT1; ++jt)
            acc1[jt] = __builtin_amdgcn_mfma_f32_16x16x32_bf16(a1[kt], p1[(kt * JT1 + jt) * 64], acc1[jt], 0, 0, 0);

    // ---- gelu(+b1) -> private LDS tile (XOR swizzle: rows spread 8 ways) ----
    char* hb = hl[wave];
    const float* b1e = b1 + e * HID;
#pragma unroll
    for (int jt = 0; jt < JT1; ++jt)
#pragma unroll
        for (int rr = 0; rr < 4; ++rr) {
            int row = lgrp * 4 + rr;
            int col = jt * 16 + lrow;
            float h = acc1[jt][rr] + b1e[col];
            float g = 0.5f * h * (1.f + erff(h * 0.70710678118654752f));
            int ad = (row * 768 + col * 2) ^ ((row & 7) << 4);
            *reinterpret_cast<short*>(hb + ad) = f2bf(g);
        }
    // same-wave LDS write->read: compiler inserts lgkmcnt; no barrier needed.

    // ---- Phase B: Y = H @ w2 ----
    f32x4 acc2[JT2];
#pragma unroll
    for (int j = 0; j < JT2; ++j) acc2[j] = (f32x4){0.f, 0.f, 0.f, 0.f};
    const short8* p2 = reinterpret_cast<const short8*>(pb2) + (size_t)e * (KT2 * JT2 * 64) + lane;
#pragma unroll
    for (int kt = 0; kt < KT2; ++kt) {
        int ab = (lrow * 768 + kt * 64 + lgrp * 16) ^ ((lrow & 7) << 4);
        short8 a2 = *reinterpret_cast<const short8*>(hb + ab);
#pragma unroll
        for (int jt = 0; jt < JT2; ++jt)
            acc2[jt] = __builtin_amdgcn_mfma_f32_16x16x32_bf16(a2, p2[(kt * JT2 + jt) * 64], acc2[jt], 0, 0, 0);
    }

    // ---- epilogue: slot[tk] = gate * exp(y) ----
    const float* b2e = b2 + e * DIM;
#pragma unroll
    for (int rr = 0; rr < 4; ++rr) {
        int rl = wave * 16 + lgrp * 4 + rr;
        if (m0 + rl < cnt) {
            int tk = ts[rl];
            float g = gs[rl];
            float* sp = slot + (size_t)tk * DIM;
#pragma unroll
            for (int jt = 0; jt < JT2; ++jt) {
                int col = jt * 16 + lrow;
                sp[col] = g * expf(acc2[jt][rr] + b2e[col]);
            }
        }
    }
}

// ---------------------------------------------------------------------------
// out[t][:] = log(slot[2t][:] + slot[2t+1][:])   (vectorized)
// ---------------------------------------------------------------------------
__global__ __launch_bounds__(256) void combine_kernel(
    const float* __restrict__ sb, float* __restrict__ out)
{
    int i = blockIdx.x * 256 + threadIdx.x;   // over N_TOK*48
    int t = i / 48;
    int j = (i - t * 48) * 4;
    const float* r = sb + (size_t)t * (2 * DIM);
    float4 a = *reinterpret_cast<const float4*>(r + j);
    float4 b = *reinterpret_cast<const float4*>(r + DIM + j);
    float4 o;
    float c;
    c = a.x + b.x; o.x = logf(c == 0.f ? EPSV : c);
    c = a.y + b.y; o.y = logf(c == 0.f ? EPSV : c);
    c = a.z + b.z; o.z = logf(c == 0.f ? EPSV : c);
    c = a.w + b.w; o.w = logf(c == 0.f ? EPSV : c);
    *reinterpret_cast<float4*>(out + (size_t)t * DIM + j) = o;
}

// ---------------------------------------------------------------------------
extern "C" void kernel_launch(void* const* d_in, const int* in_sizes, int n_in,
                              void* d_out, int out_size, void* d_ws, size_t ws_size,
                              hipStream_t stream) {
    const float* x   = (const float*)d_in[0];
    const float* emb = (const float*)d_in[1];
    const float* wg  = (const float*)d_in[2];
    const float* w1  = (const float*)d_in[3];
    const float* b1  = (const float*)d_in[4];
    const float* w2  = (const float*)d_in[5];
    const float* b2  = (const float*)d_in[6];
    float* out = (float*)d_out;

    char* ws = (char*)d_ws;
    size_t off = 0;
    auto alloc = [&](size_t n) { size_t p = off; off = (off + n + 255) & ~(size_t)255; return p; };
    int*   counts = (int*)  (ws + alloc(256));
    int*   toks   = (int*)  (ws + alloc((size_t)NEXP * N_TOK * 4));
    float* gates  = (float*)(ws + alloc((size_t)NEXP * N_TOK * 4));
    short* pb1    = (short*)(ws + alloc((size_t)NEXP * DIM * HID * 2));
    short* pb2    = (short*)(ws + alloc((size_t)NEXP * HID * DIM * 2));
    float* slot   = (float*)(ws + alloc((size_t)2 * N_TOK * DIM * 4));   // 50.3 MB
    size_t xoff   = alloc((size_t)N_TOK * DIM * 2);
    short* xb     = (short*)(ws + xoff);
    bool use_xb = (ws_size >= off);

    hipMemsetAsync(counts, 0, NEXP * sizeof(int), stream);

    const int Q = NEXP * DIM * HID / 4;
    pack_kernel<<<(2 * Q) / 256, 256, 0, stream>>>(w1, w2, pb1, pb2);

    if (use_xb)
        gate_kernel<true><<<N_TOK / 64, 256, 0, stream>>>(x, emb, wg, counts, toks, gates, xb);
    else
        gate_kernel<false><<<N_TOK / 64, 256, 0, stream>>>(x, emb, wg, counts, toks, gates, nullptr);

    if (use_xb)
        fused_kernel<true><<<NEXP * 512, 256, 0, stream>>>(x, xb, pb1, pb2, b1, b2, counts, toks, gates, slot);
    else
        fused_kernel<false><<<NEXP * 512, 256, 0, stream>>>(x, nullptr, pb1, pb2, b1, b2, counts, toks, gates, slot);

    combine_kernel<<<(N_TOK * 48) / 256, 256, 0, stream>>>(slot, out);
}